// Round 15
// baseline (786.056 us; speedup 1.0000x reference)
//
#include <hip/hip_runtime.h>
#include <math.h>

#define BATCH 65536
#define FDIM 16
#define CDIM 128
#define HDIM 256
#define NL 8
#define KBINS 8
#define TDIM 8
#define PD 23
#define TBV 3.0f
#define K1 160      // GEMM1 K: 128 ctx + 8 xi + 24 zero
#define N3 184      // real N of GEMM3
#define N3P 192     // padded N of GEMM3
#define PSTR 197    // p LDS row stride (f32 words)
#define MR 64       // rows per row-block
#define XSTR 40     // sXi row stride (f16)

typedef _Float16 f16;
typedef __attribute__((ext_vector_type(8))) _Float16 f16x8;
typedef __attribute__((ext_vector_type(4))) float f32x4;

// ---------------- weight conversion (transposed to [N][K], split hi/lo) ----
__global__ __launch_bounds__(256)
void conv_w1_kernel(const float* __restrict__ W1,
                    f16* __restrict__ Wh, f16* __restrict__ Wl) {
    int idx = blockIdx.x * 256 + threadIdx.x;
    if (idx >= NL * HDIM * K1) return;
    int l = idx / (HDIM * K1);
    int rem = idx - l * (HDIM * K1);
    int n = rem / K1;
    int k = rem - n * K1;
    int row = (k < 128) ? (8 + k) : ((k < 136) ? (k - 128) : -1);
    float v = (row >= 0) ? W1[((size_t)l * 136 + row) * HDIM + n] : 0.f;
    f16 hv = (f16)v;
    Wh[idx] = hv; Wl[idx] = (f16)(v - (float)hv);
}

__global__ __launch_bounds__(256)
void conv_w2_kernel(const float* __restrict__ W2,
                    f16* __restrict__ Wh, f16* __restrict__ Wl) {
    int idx = blockIdx.x * 256 + threadIdx.x;
    if (idx >= NL * HDIM * HDIM) return;
    int l = idx / (HDIM * HDIM);
    int rem = idx - l * (HDIM * HDIM);
    int n = rem >> 8;
    int k = rem & 255;
    float v = W2[((size_t)l * HDIM + k) * HDIM + n];
    f16 hv = (f16)v;
    Wh[idx] = hv; Wl[idx] = (f16)(v - (float)hv);
}

__global__ __launch_bounds__(256)
void conv_w3_kernel(const float* __restrict__ W3,
                    f16* __restrict__ Wh, f16* __restrict__ Wl) {
    int idx = blockIdx.x * 256 + threadIdx.x;
    if (idx >= NL * N3P * HDIM) return;
    int l = idx / (N3P * HDIM);
    int rem = idx - l * (N3P * HDIM);
    int n = rem >> 8;
    int k = rem & 255;
    float v = (n < N3) ? W3[((size_t)l * HDIM + k) * N3 + n] : 0.f;
    f16 hv = (f16)v;
    Wh[idx] = hv; Wl[idx] = (f16)(v - (float)hv);
}

__global__ __launch_bounds__(256)
void conv_ctx_kernel(const float* __restrict__ ctx,
                     f16* __restrict__ ch, f16* __restrict__ cl) {
    size_t idx = ((size_t)blockIdx.x * 256 + threadIdx.x) * 4;
    if (idx >= (size_t)BATCH * CDIM) return;
    float4 v = *(const float4*)&ctx[idx];
    f16 h;
    h = (f16)v.x; ch[idx + 0] = h; cl[idx + 0] = (f16)(v.x - (float)h);
    h = (f16)v.y; ch[idx + 1] = h; cl[idx + 1] = (f16)(v.y - (float)h);
    h = (f16)v.z; ch[idx + 2] = h; cl[idx + 2] = (f16)(v.z - (float)h);
    h = (f16)v.w; ch[idx + 3] = h; cl[idx + 3] = (f16)(v.w - (float)h);
}

__device__ __forceinline__ float softplusf(float v) {
    return fmaxf(v, 0.f) + log1pf(expf(-fabsf(v)));
}

__device__ __forceinline__ void gld16(const f16* src, f16* dst) {
    __builtin_amdgcn_global_load_lds(
        (const __attribute__((address_space(1))) unsigned int*)src,
        (__attribute__((address_space(3))) unsigned int*)dst, 16, 0, 0);
}

// ---------------- fused flow kernel ----------------
// Persistent: grid 256 (1 WG/CU), 1024 threads (16 waves = 4 row-quarters x
// 4 col-groups => 4 waves/SIMD). Each WG loops 4 row-blocks of 64 rows.
// Weights async-staged into LDS (double-buffered), ctx resident, h1/h2
// single f16, xi split-f16. Math order identical to the 512-thread version.
__global__ __launch_bounds__(1024, 1)
void flow_kernel(const float* __restrict__ in,
                 const f16* __restrict__ ctxh, const f16* __restrict__ ctxl,
                 const f16* __restrict__ W1h, const f16* __restrict__ W1l,
                 const f16* __restrict__ W2h, const f16* __restrict__ W2l,
                 const f16* __restrict__ W3h, const f16* __restrict__ W3l,
                 const float* __restrict__ b1, const float* __restrict__ b2,
                 const float* __restrict__ b3, const int* __restrict__ perms,
                 float* __restrict__ out) {
    __shared__ __align__(16) char arena[98304];   // sH(32K) | sB(2buf x 2pl x 16K)
    __shared__ __align__(16) f16 sCtx[2][8192];   // 32KB chunk-major: [g][row]
    __shared__ __align__(16) f16 sXi[2][MR * XSTR]; // 10.2KB
    __shared__ float sX[2][MR][17];
    __shared__ float sY[MR][9];
    __shared__ float sLd[MR][9];
    __shared__ float sLdet[MR];
    __shared__ int   sPerm[(NL - 1) * FDIM];

    f16* sH = (f16*)arena;
    float* sP = (float*)arena;

    const int tid = threadIdx.x;
    const int lane = tid & 63;
    const int w = tid >> 6;                      // 0..15
    const int wrq = w >> 2;                      // row quarter 0..3
    const int wcg = w & 3;                       // col group 0..3
    const int lr = lane & 15, lh = lane >> 4;
    const int bid = blockIdx.x;
    const int wgid = (bid & 7) * 32 + (bid >> 3);   // XCD swizzle, grid 256

    // B staging (1024 threads): slot = tid, col = tid>>2, seg = tid&3
    const int scol0 = tid >> 2;
    const int ssegsw = (tid & 3) ^ (scol0 & 3);
    // B read: byte = col*64 + ((lh ^ (col&3))<<4); col&3 == lr&3 here
    const int bxor = (lh ^ (lr & 3)) << 4;

    auto sBh = [&](int buf) -> f16* { return (f16*)(arena + 32768 + buf * 32768); };
    auto sBl = [&](int buf) -> f16* { return (f16*)(arena + 32768 + buf * 32768 + 16384); };

    auto stageB = [&](const f16* Wh, const f16* Wl, int buf, int kt, int KD, int nSlots) {
        if (tid < nSlots) {
            f16* dh = sBh(buf) + tid * 8;
            f16* dl = sBl(buf) + tid * 8;
            const f16* sh = Wh + (size_t)scol0 * KD + kt * 32 + ssegsw * 8;
            const f16* sl = Wl + (size_t)scol0 * KD + kt * 32 + ssegsw * 8;
            gld16(sh, dh);
            gld16(sl, dl);
        }
    };

    for (int rb = 0; rb < 4; ++rb) {
        const int rbase = (rb * 256 + wgid) * MR;
        __syncthreads();   // protect sX/sLdet/sCtx reuse across row-blocks

        // ---- init x, ldet, perms ----
        {
            int r = tid >> 4, c = tid & 15;
            float v = in[(size_t)(rbase + r) * FDIM + c];
            sX[0][r][c] = fminf(fmaxf(v, -1.f), 1.f);
        }
        if (tid < MR) sLdet[tid] = 0.f;
        if (rb == 0 && tid < (NL - 1) * FDIM) sPerm[tid] = perms[tid];

        // ---- stage ctx (resident all 8 layers): chunk-major [g][row] ----
        // slot (g,row) holds ctx[row ^ ((g&3)<<2)][g*8..g*8+7]
        {
            int g = tid >> 6, row = tid & 63;
            int rsrc = row ^ ((g & 3) << 2);
            const f16* srch = ctxh + (size_t)(rbase + rsrc) * CDIM + g * 8;
            const f16* srcl = ctxl + (size_t)(rbase + rsrc) * CDIM + g * 8;
            gld16(srch, &sCtx[0][tid * 8]);
            gld16(srcl, &sCtx[1][tid * 8]);
        }

        int cur = 0;
        for (int l = 0; l < NL; ++l) {
            __syncthreads();   // drains ctx stage (l==0) / guards rebuild & sP
            // ---- xi (split) into sXi + zero pad ----
            if (tid < MR) {
                int r = tid, off = 1 - (l & 1);
                #pragma unroll
                for (int k = 0; k < 8; ++k) {
                    float v = sX[cur][r][2 * k + off];
                    f16 hv = (f16)v;
                    sXi[0][r * XSTR + k] = hv;
                    sXi[1][r * XSTR + k] = (f16)(v - (float)hv);
                }
                #pragma unroll
                for (int k = 8; k < 32; ++k) {
                    sXi[0][r * XSTR + k] = (f16)0.f;
                    sXi[1][r * XSTR + k] = (f16)0.f;
                }
            }
            const f16* W1hL = W1h + (size_t)l * HDIM * K1;
            const f16* W1lL = W1l + (size_t)l * HDIM * K1;
            const f16* W2hL = W2h + (size_t)l * HDIM * HDIM;
            const f16* W2lL = W2l + (size_t)l * HDIM * HDIM;
            const f16* W3hL = W3h + (size_t)l * N3P * HDIM;
            const f16* W3lL = W3l + (size_t)l * N3P * HDIM;
            stageB(W1hL, W1lL, 0, 0, K1, 1024);
            __syncthreads();

            // ================= GEMM1: 256 cols, K=160 (A split) ============
            {
                f32x4 acc[4];
                #pragma unroll
                for (int j = 0; j < 4; ++j) acc[j] = (f32x4){0.f, 0.f, 0.f, 0.f};
                int buf = 0;
                for (int kt = 0; kt < 5; ++kt) {
                    if (kt < 4) stageB(W1hL, W1lL, buf ^ 1, kt + 1, K1, 1024);
                    f16x8 ah, al;
                    int row = wrq * 16 + lr;
                    if (kt < 4) {
                        int gb = (kt * 4 + lh) * 1024;
                        int byo = gb + ((row ^ (lh << 2)) << 4);
                        ah = *(const f16x8*)((const char*)&sCtx[0][0] + byo);
                        al = *(const f16x8*)((const char*)&sCtx[1][0] + byo);
                    } else {
                        ah = *(const f16x8*)&sXi[0][row * XSTR + lh * 8];
                        al = *(const f16x8*)&sXi[1][row * XSTR + lh * 8];
                    }
                    const char* bbh = (const char*)sBh(buf);
                    const char* bbl = (const char*)sBl(buf);
                    __builtin_amdgcn_s_setprio(1);
                    #pragma unroll
                    for (int j = 0; j < 4; ++j) {
                        int cb = (wcg * 64 + j * 16 + lr) * 64 + bxor;
                        f16x8 bh = *(const f16x8*)(bbh + cb);
                        f16x8 bl = *(const f16x8*)(bbl + cb);
                        acc[j] = __builtin_amdgcn_mfma_f32_16x16x32_f16(ah, bh, acc[j], 0, 0, 0);
                        acc[j] = __builtin_amdgcn_mfma_f32_16x16x32_f16(ah, bl, acc[j], 0, 0, 0);
                        acc[j] = __builtin_amdgcn_mfma_f32_16x16x32_f16(al, bh, acc[j], 0, 0, 0);
                    }
                    __builtin_amdgcn_s_setprio(0);
                    __syncthreads();
                    buf ^= 1;
                }
                // h1 = relu(acc+b1) -> sH (single f16)
                #pragma unroll
                for (int j = 0; j < 4; ++j) {
                    int col = wcg * 64 + j * 16 + lr;
                    float bv = b1[l * HDIM + col];
                    #pragma unroll
                    for (int q = 0; q < 4; ++q) {
                        float v = fmaxf(acc[j][q] + bv, 0.f);
                        int row = wrq * 16 + lh * 4 + q;
                        int e = ((row << 8) + col) ^ ((row & 7) << 3);
                        sH[e] = (f16)v;
                    }
                }
            }
            stageB(W2hL, W2lL, 0, 0, HDIM, 1024);
            __syncthreads();

            // ================= GEMM2: 256 cols, K=256 (A single) ===========
            {
                f32x4 acc[4];
                #pragma unroll
                for (int j = 0; j < 4; ++j) acc[j] = (f32x4){0.f, 0.f, 0.f, 0.f};
                int buf = 0;
                for (int kt = 0; kt < 8; ++kt) {
                    if (kt < 7) stageB(W2hL, W2lL, buf ^ 1, kt + 1, HDIM, 1024);
                    int k0 = kt * 32 + lh * 8;
                    int row = wrq * 16 + lr;
                    int e = ((row << 8) + k0) ^ ((row & 7) << 3);
                    f16x8 ah = *(const f16x8*)&sH[e];
                    const char* bbh = (const char*)sBh(buf);
                    const char* bbl = (const char*)sBl(buf);
                    __builtin_amdgcn_s_setprio(1);
                    #pragma unroll
                    for (int j = 0; j < 4; ++j) {
                        int cb = (wcg * 64 + j * 16 + lr) * 64 + bxor;
                        f16x8 bh = *(const f16x8*)(bbh + cb);
                        f16x8 bl = *(const f16x8*)(bbl + cb);
                        acc[j] = __builtin_amdgcn_mfma_f32_16x16x32_f16(ah, bh, acc[j], 0, 0, 0);
                        acc[j] = __builtin_amdgcn_mfma_f32_16x16x32_f16(ah, bl, acc[j], 0, 0, 0);
                    }
                    __builtin_amdgcn_s_setprio(0);
                    __syncthreads();
                    buf ^= 1;
                }
                // h2 = relu(acc+b2) -> sH
                #pragma unroll
                for (int j = 0; j < 4; ++j) {
                    int col = wcg * 64 + j * 16 + lr;
                    float bv = b2[l * HDIM + col];
                    #pragma unroll
                    for (int q = 0; q < 4; ++q) {
                        float v = fmaxf(acc[j][q] + bv, 0.f);
                        int row = wrq * 16 + lh * 4 + q;
                        int e = ((row << 8) + col) ^ ((row & 7) << 3);
                        sH[e] = (f16)v;
                    }
                }
            }
            stageB(W3hL, W3lL, 0, 0, HDIM, 768);
            __syncthreads();

            // ================= GEMM3: 192 cols, K=256 (A single) ===========
            {
                f32x4 acc3[3];
                #pragma unroll
                for (int j = 0; j < 3; ++j) acc3[j] = (f32x4){0.f, 0.f, 0.f, 0.f};
                int buf = 0;
                for (int kt = 0; kt < 8; ++kt) {
                    if (kt < 7) stageB(W3hL, W3lL, buf ^ 1, kt + 1, HDIM, 768);
                    int k0 = kt * 32 + lh * 8;
                    int row = wrq * 16 + lr;
                    int e = ((row << 8) + k0) ^ ((row & 7) << 3);
                    f16x8 ah = *(const f16x8*)&sH[e];
                    const char* bbh = (const char*)sBh(buf);
                    const char* bbl = (const char*)sBl(buf);
                    __builtin_amdgcn_s_setprio(1);
                    #pragma unroll
                    for (int j = 0; j < 3; ++j) {
                        int cb = (wcg * 48 + j * 16 + lr) * 64 + bxor;
                        f16x8 bh = *(const f16x8*)(bbh + cb);
                        f16x8 bl = *(const f16x8*)(bbl + cb);
                        acc3[j] = __builtin_amdgcn_mfma_f32_16x16x32_f16(ah, bh, acc3[j], 0, 0, 0);
                        acc3[j] = __builtin_amdgcn_mfma_f32_16x16x32_f16(ah, bl, acc3[j], 0, 0, 0);
                    }
                    __builtin_amdgcn_s_setprio(0);
                    __syncthreads();
                    buf ^= 1;
                }
                // p = acc3 + b3 -> sP (overlays sH + dead sB)
                #pragma unroll
                for (int j = 0; j < 3; ++j) {
                    int col = wcg * 48 + j * 16 + lr;
                    float bv = (col < N3) ? b3[l * N3 + col] : 0.f;
                    #pragma unroll
                    for (int q = 0; q < 4; ++q) {
                        int row = wrq * 16 + lh * 4 + q;
                        sP[row * PSTR + col] = acc3[j][q] + bv;
                    }
                }
            }
            __syncthreads();

            // ===== spline: one (row,t) per thread (512 active) =====
            if (tid < 512) {
                int r = tid & 63, t = tid >> 6;
                float xin = sX[cur][r][2 * t + (l & 1)];
                const float* pp = &sP[r * PSTR + t * PD];
                bool inside = (xin >= -TBV) && (xin <= TBV);
                float xs = fminf(fmaxf(xin, -TBV), TBV);

                float e0, e1, e2, e3, e4, e5, e6, e7;
                {
                    float a0 = pp[0], a1 = pp[1], a2 = pp[2], a3 = pp[3];
                    float a4 = pp[4], a5 = pp[5], a6 = pp[6], a7 = pp[7];
                    float m = fmaxf(fmaxf(fmaxf(a0, a1), fmaxf(a2, a3)),
                                    fmaxf(fmaxf(a4, a5), fmaxf(a6, a7)));
                    e0 = expf(a0 - m); e1 = expf(a1 - m); e2 = expf(a2 - m); e3 = expf(a3 - m);
                    e4 = expf(a4 - m); e5 = expf(a5 - m); e6 = expf(a6 - m); e7 = expf(a7 - m);
                }
                float swv = ((e0 + e1) + (e2 + e3)) + ((e4 + e5) + (e6 + e7));
                float cwc = (1.f - 0.001f * KBINS) / swv;
                float x0 = -TBV, x1 = TBV;
                int idx = 0;
                bool done = false;
                {
                    float cs = 0.f;
                    float ee[7] = {e0, e1, e2, e3, e4, e5, e6};
                    #pragma unroll
                    for (int k = 0; k < 7; ++k) {
                        cs += 0.001f + cwc * ee[k];
                        float nxt = 2.f * TBV * cs - TBV;
                        bool ge = (xs >= nxt);
                        x0 = ge ? nxt : x0;
                        idx += ge ? 1 : 0;
                        x1 = (!ge && !done) ? nxt : x1;
                        done = done || !ge;
                    }
                }
                float y0 = -TBV, y1 = TBV;
                {
                    float a0 = pp[8], a1 = pp[9], a2 = pp[10], a3 = pp[11];
                    float a4 = pp[12], a5 = pp[13], a6 = pp[14], a7 = pp[15];
                    float m = fmaxf(fmaxf(fmaxf(a0, a1), fmaxf(a2, a3)),
                                    fmaxf(fmaxf(a4, a5), fmaxf(a6, a7)));
                    float f0 = expf(a0 - m), f1 = expf(a1 - m), f2 = expf(a2 - m), f3 = expf(a3 - m);
                    float f4 = expf(a4 - m), f5 = expf(a5 - m), f6 = expf(a6 - m), f7 = expf(a7 - m);
                    float shv = ((f0 + f1) + (f2 + f3)) + ((f4 + f5) + (f6 + f7));
                    float chc = (1.f - 0.001f * KBINS) / shv;
                    float cs = 0.f;
                    float ff[7] = {f0, f1, f2, f3, f4, f5, f6};
                    #pragma unroll
                    for (int k = 0; k < 7; ++k) {
                        cs += 0.001f + chc * ff[k];
                        float nxt = 2.f * TBV * cs - TBV;
                        y0 = (k < idx) ? nxt : y0;
                        y1 = (k == idx) ? nxt : y1;
                    }
                }
                float udm = pp[16 + (idx > 0 ? idx - 1 : 0)];
                float udp = pp[16 + (idx < 7 ? idx : 6)];
                float d0 = (idx > 0) ? 0.001f + softplusf(udm) : 1.f;
                float d1 = (idx < 7) ? 0.001f + softplusf(udp) : 1.f;

                float bw = x1 - x0, bh2 = y1 - y0;
                float delta = bh2 / bw;
                float th = (xs - x0) / bw;
                float th1m = th * (1.f - th);
                float num = bh2 * (delta * th * th + d0 * th1m);
                float den = delta + (d0 + d1 - 2.f * delta) * th1m;
                float y = y0 + num / den;
                float omth = 1.f - th;
                float dnum = delta * delta * (d1 * th * th + 2.f * delta * th1m + d0 * omth * omth);
                float ldv = logf(dnum) - 2.f * logf(den);
                sY[r][t] = inside ? y : xin;
                sLd[r][t] = inside ? ldv : 0.f;
            }
            __syncthreads();

            // ===== rebuild x (+perm) and ldet: 1 feature per thread =====
            {
                int r = tid >> 4, f = tid & 15;
                if (l < NL - 1) {
                    int g = sPerm[l * FDIM + f];
                    float v = ((g & 1) == (l & 1)) ? sY[r][g >> 1] : sX[cur][r][g];
                    sX[cur ^ 1][r][f] = v;
                    if (f == 0) {
                        float s = 0.f;
                        #pragma unroll
                        for (int t = 0; t < 8; ++t) s += sLd[r][t];
                        sLdet[r] += s;
                    }
                } else {
                    float v = ((f & 1) == (l & 1)) ? sY[r][f >> 1] : sX[cur][r][f];
                    out[(size_t)(rbase + r) * FDIM + f] = fminf(fmaxf(v, -1.f), 1.f);
                    if (f == 0) {
                        float s = 0.f;
                        #pragma unroll
                        for (int t = 0; t < 8; ++t) s += sLd[r][t];
                        out[(size_t)BATCH * FDIM + rbase + r] = sLdet[r] + s;
                    }
                }
            }
            cur ^= 1;
        }
    }
}

extern "C" void kernel_launch(void* const* d_in, const int* in_sizes, int n_in,
                              void* d_out, int out_size, void* d_ws, size_t ws_size,
                              hipStream_t stream) {
    (void)in_sizes; (void)n_in; (void)out_size; (void)ws_size;
    const float* inputs  = (const float*)d_in[0];
    const float* context = (const float*)d_in[1];
    const float* W1 = (const float*)d_in[2];
    const float* b1 = (const float*)d_in[3];
    const float* W2 = (const float*)d_in[4];
    const float* b2 = (const float*)d_in[5];
    const float* W3 = (const float*)d_in[6];
    const float* b3 = (const float*)d_in[7];
    const int*   perms = (const int*)d_in[8];
    float* out = (float*)d_out;

    f16* W1h = (f16*)d_ws;
    f16* W1l = W1h + (size_t)NL * HDIM * K1;
    f16* W2h = W1l + (size_t)NL * HDIM * K1;
    f16* W2l = W2h + (size_t)NL * HDIM * HDIM;
    f16* W3h = W2l + (size_t)NL * HDIM * HDIM;
    f16* W3l = W3h + (size_t)NL * N3P * HDIM;
    f16* ctxh = W3l + (size_t)NL * N3P * HDIM;
    f16* ctxl = ctxh + (size_t)BATCH * CDIM;

    int n1 = NL * HDIM * K1;
    conv_w1_kernel<<<(n1 + 255) / 256, 256, 0, stream>>>(W1, W1h, W1l);
    int n2 = NL * HDIM * HDIM;
    conv_w2_kernel<<<(n2 + 255) / 256, 256, 0, stream>>>(W2, W2h, W2l);
    int n3 = NL * N3P * HDIM;
    conv_w3_kernel<<<(n3 + 255) / 256, 256, 0, stream>>>(W3, W3h, W3l);
    int nc = BATCH * CDIM / 4;
    conv_ctx_kernel<<<(nc + 255) / 256, 256, 0, stream>>>(context, ctxh, ctxl);

    flow_kernel<<<256, 1024, 0, stream>>>(
        inputs, ctxh, ctxl, W1h, W1l, W2h, W2l, W3h, W3l,
        b1, b2, b3, perms, out);
}

// Round 16
// 743.825 us; speedup vs baseline: 1.0568x; 1.0568x over previous
//
#include <hip/hip_runtime.h>
#include <math.h>

#define BATCH 65536
#define FDIM 16
#define CDIM 128
#define HDIM 256
#define NL 8
#define KBINS 8
#define TDIM 8
#define PD 23
#define TBV 3.0f
#define K1 160      // GEMM1 K: 128 ctx + 8 xi + 24 zero
#define N3 184      // real N of GEMM3
#define N3P 192     // padded N of GEMM3
#define PSTR 197    // p LDS row stride (f32 words)
#define MR 64       // rows per row-block
#define XSTR 40     // sXi row stride (f16)

typedef _Float16 f16;
typedef __attribute__((ext_vector_type(8))) _Float16 f16x8;
typedef __attribute__((ext_vector_type(4))) float f32x4;

// ---------------- weight conversion (transposed to [N][K], split hi/lo) ----
__global__ __launch_bounds__(256)
void conv_w1_kernel(const float* __restrict__ W1,
                    f16* __restrict__ Wh, f16* __restrict__ Wl) {
    int idx = blockIdx.x * 256 + threadIdx.x;
    if (idx >= NL * HDIM * K1) return;
    int l = idx / (HDIM * K1);
    int rem = idx - l * (HDIM * K1);
    int n = rem / K1;
    int k = rem - n * K1;
    int row = (k < 128) ? (8 + k) : ((k < 136) ? (k - 128) : -1);
    float v = (row >= 0) ? W1[((size_t)l * 136 + row) * HDIM + n] : 0.f;
    f16 hv = (f16)v;
    Wh[idx] = hv; Wl[idx] = (f16)(v - (float)hv);
}

__global__ __launch_bounds__(256)
void conv_w2_kernel(const float* __restrict__ W2,
                    f16* __restrict__ Wh, f16* __restrict__ Wl) {
    int idx = blockIdx.x * 256 + threadIdx.x;
    if (idx >= NL * HDIM * HDIM) return;
    int l = idx / (HDIM * HDIM);
    int rem = idx - l * (HDIM * HDIM);
    int n = rem >> 8;
    int k = rem & 255;
    float v = W2[((size_t)l * HDIM + k) * HDIM + n];
    f16 hv = (f16)v;
    Wh[idx] = hv; Wl[idx] = (f16)(v - (float)hv);
}

__global__ __launch_bounds__(256)
void conv_w3_kernel(const float* __restrict__ W3,
                    f16* __restrict__ Wh, f16* __restrict__ Wl) {
    int idx = blockIdx.x * 256 + threadIdx.x;
    if (idx >= NL * N3P * HDIM) return;
    int l = idx / (N3P * HDIM);
    int rem = idx - l * (N3P * HDIM);
    int n = rem >> 8;
    int k = rem & 255;
    float v = (n < N3) ? W3[((size_t)l * HDIM + k) * N3 + n] : 0.f;
    f16 hv = (f16)v;
    Wh[idx] = hv; Wl[idx] = (f16)(v - (float)hv);
}

__global__ __launch_bounds__(256)
void conv_ctx_kernel(const float* __restrict__ ctx,
                     f16* __restrict__ ch, f16* __restrict__ cl) {
    size_t idx = ((size_t)blockIdx.x * 256 + threadIdx.x) * 4;
    if (idx >= (size_t)BATCH * CDIM) return;
    float4 v = *(const float4*)&ctx[idx];
    f16 h;
    h = (f16)v.x; ch[idx + 0] = h; cl[idx + 0] = (f16)(v.x - (float)h);
    h = (f16)v.y; ch[idx + 1] = h; cl[idx + 1] = (f16)(v.y - (float)h);
    h = (f16)v.z; ch[idx + 2] = h; cl[idx + 2] = (f16)(v.z - (float)h);
    h = (f16)v.w; ch[idx + 3] = h; cl[idx + 3] = (f16)(v.w - (float)h);
}

__device__ __forceinline__ float softplusf(float v) {
    return fmaxf(v, 0.f) + log1pf(expf(-fabsf(v)));
}

__device__ __forceinline__ void gld16(const f16* src, f16* dst) {
    __builtin_amdgcn_global_load_lds(
        (const __attribute__((address_space(1))) unsigned int*)src,
        (__attribute__((address_space(3))) unsigned int*)dst, 16, 0, 0);
}

template<int N> __device__ __forceinline__ void vmw() {
    asm volatile("s_waitcnt vmcnt(%0)" :: "n"(N) : "memory");
}
__device__ __forceinline__ void barr() {
    __builtin_amdgcn_s_barrier();
    __builtin_amdgcn_sched_barrier(0);
}
__device__ __forceinline__ void lgkm_bar() {
    asm volatile("s_waitcnt lgkmcnt(0)" ::: "memory");
    __builtin_amdgcn_s_barrier();
    __builtin_amdgcn_sched_barrier(0);
}

// ---------------- fused flow kernel ----------------
// Persistent: grid 256 (1 WG/CU), 512 threads (8 waves = 2 row-halves x 4
// col-groups). 3-buffer weight pipeline: phase kt stages kt+2, counted
// vmcnt (8/4/0), raw barriers — loads span 2 phases. ctx restaged per layer
// into the sH region (xor-swizzled). Biases in LDS. h1/h2 single f16.
__global__ __launch_bounds__(512, 1)
void flow_kernel(const float* __restrict__ in,
                 const f16* __restrict__ ctxh, const f16* __restrict__ ctxl,
                 const f16* __restrict__ W1h, const f16* __restrict__ W1l,
                 const f16* __restrict__ W2h, const f16* __restrict__ W2l,
                 const f16* __restrict__ W3h, const f16* __restrict__ W3l,
                 const float* __restrict__ b1, const float* __restrict__ b2,
                 const float* __restrict__ b3, const int* __restrict__ perms,
                 float* __restrict__ out) {
    // arena: [0,32K) ctx(2pl 16K) / sH / sP-head | [32K..128K) sB0,sB1,sB2
    __shared__ __align__(16) char arena[131072];
    __shared__ __align__(16) f16 sXi[2][MR * XSTR];   // 10.2KB
    __shared__ float sX[2][MR][17];
    __shared__ float sY[MR][9];
    __shared__ float sLd[MR][9];
    __shared__ float sLdet[MR];
    __shared__ float sBias[768];
    __shared__ int   sPerm[(NL - 1) * FDIM];

    f16* sH = (f16*)arena;
    float* sP = (float*)arena;

    const int tid = threadIdx.x;
    const int lane = tid & 63;
    const int w = tid >> 6;                      // 0..7
    const int wrh = w >> 2;                      // row half
    const int wcg = w & 3;                       // col group
    const int lr = lane & 15, lh = lane >> 4;
    const int bid = blockIdx.x;
    const int wgid = (bid & 7) * 32 + (bid >> 3);   // XCD swizzle, grid 256

    const int scol0 = tid >> 2;                  // staging col (first 128)
    const int ssegsw = (tid & 3) ^ (scol0 & 3);  // pre-swizzled k-segment
    const int bxor = (lh ^ (lr & 3)) << 4;       // B read de-swizzle

    char* const bufs[3] = { arena + 32768, arena + 65536, arena + 98304 };

    auto stageB = [&](const f16* Wh, const f16* Wl, char* tgt, int kt, int KD) {
        const f16* sh = Wh + (size_t)scol0 * KD + kt * 32 + ssegsw * 8;
        const f16* sl = Wl + (size_t)scol0 * KD + kt * 32 + ssegsw * 8;
        f16* dh = (f16*)(tgt + tid * 16);
        f16* dl = (f16*)(tgt + 16384 + tid * 16);
        gld16(sh, dh);
        gld16(sh + (size_t)128 * KD, (f16*)((char*)dh + 8192));
        gld16(sl, dl);
        gld16(sl + (size_t)128 * KD, (f16*)((char*)dl + 8192));
    };

    for (int rb = 0; rb < 4; ++rb) {
        const int rbase = (rb * 256 + wgid) * MR;
        __syncthreads();   // full drain between row-blocks

        // ---- init x, ldet, perms ----
        {
            int r = tid >> 3, c2 = (tid & 7) * 2;
            float2 v = *(const float2*)&in[(size_t)(rbase + r) * FDIM + c2];
            sX[0][r][c2 + 0] = fminf(fmaxf(v.x, -1.f), 1.f);
            sX[0][r][c2 + 1] = fminf(fmaxf(v.y, -1.f), 1.f);
        }
        if (tid < MR) sLdet[tid] = 0.f;
        if (rb == 0 && tid < (NL - 1) * FDIM) sPerm[tid] = perms[tid];

        int cur = 0;
        for (int l = 0; l < NL; ++l) {
            lgkm_bar();   // publish rebuild/init LDS writes

            // ---- biases -> LDS (uniform 2 vmem loads/thread) ----
            {
                float bv1 = (tid < 256) ? b1[l * HDIM + tid]
                                        : b2[l * HDIM + (tid - 256)];
                float bv3 = b3[l * N3 + (tid < N3 ? tid : N3 - 1)];
                sBias[tid] = bv1;
                if (tid < N3) sBias[512 + tid] = bv3;
            }
            // ---- xi (split) into sXi + zero pad ----
            if (tid < MR) {
                int r = tid, off = 1 - (l & 1);
                #pragma unroll
                for (int k = 0; k < 8; ++k) {
                    float v = sX[cur][r][2 * k + off];
                    f16 hv = (f16)v;
                    sXi[0][r * XSTR + k] = hv;
                    sXi[1][r * XSTR + k] = (f16)(v - (float)hv);
                }
                #pragma unroll
                for (int k = 8; k < 32; ++k) {
                    sXi[0][r * XSTR + k] = (f16)0.f;
                    sXi[1][r * XSTR + k] = (f16)0.f;
                }
            }
            // ---- stage ctx into arena[0,32K): row-major, swizzled src ----
            #pragma unroll
            for (int s = 0; s < 4; ++s) {
                int slot = s * 512 + tid;
                int p = slot >> 10, sp = slot & 1023;
                int row = sp >> 4, blk = sp & 15;
                const f16* src = (p ? ctxl : ctxh)
                               + (size_t)(rbase + row) * CDIM + (blk ^ (row & 7)) * 8;
                gld16(src, (f16*)(arena + slot * 16));
            }
            const f16* W1hL = W1h + (size_t)l * HDIM * K1;
            const f16* W1lL = W1l + (size_t)l * HDIM * K1;
            const f16* W2hL = W2h + (size_t)l * HDIM * HDIM;
            const f16* W2lL = W2l + (size_t)l * HDIM * HDIM;
            const f16* W3hL = W3h + (size_t)l * N3P * HDIM;
            const f16* W3lL = W3l + (size_t)l * N3P * HDIM;
            stageB(W1hL, W1lL, bufs[0], 0, K1);
            stageB(W1hL, W1lL, bufs[1], 1, K1);
            lgkm_bar();   // publish xi/bias LDS writes (staging keeps flying)

            // ================= GEMM1: K=160, 5 phases, A split ============
            f32x4 acc[2][4];
            #pragma unroll
            for (int i = 0; i < 2; ++i)
                #pragma unroll
                for (int j = 0; j < 4; ++j) acc[i][j] = (f32x4){0.f, 0.f, 0.f, 0.f};
            #pragma unroll
            for (int kt = 0; kt < 5; ++kt) {
                if (kt + 2 < 5) stageB(W1hL, W1lL, bufs[(kt + 2) % 3], kt + 2, K1);
                if (kt < 3) vmw<8>(); else if (kt == 3) vmw<4>(); else vmw<0>();
                barr();
                f16x8 ah[2], al[2];
                if (kt < 4) {
                    #pragma unroll
                    for (int i = 0; i < 2; ++i) {
                        int row = wrh * 32 + i * 16 + lr;
                        int byo = row * 256 + ((kt * 64 + lh * 16) ^ ((row & 7) << 4));
                        ah[i] = *(const f16x8*)(arena + byo);
                        al[i] = *(const f16x8*)(arena + 16384 + byo);
                    }
                } else {
                    #pragma unroll
                    for (int i = 0; i < 2; ++i) {
                        int row = wrh * 32 + i * 16 + lr;
                        ah[i] = *(const f16x8*)&sXi[0][row * XSTR + lh * 8];
                        al[i] = *(const f16x8*)&sXi[1][row * XSTR + lh * 8];
                    }
                }
                const char* bb = bufs[kt % 3];
                __builtin_amdgcn_s_setprio(1);
                #pragma unroll
                for (int j = 0; j < 4; ++j) {
                    int cb = (wcg * 64 + j * 16 + lr) * 64 + bxor;
                    f16x8 bh = *(const f16x8*)(bb + cb);
                    f16x8 bl = *(const f16x8*)(bb + 16384 + cb);
                    #pragma unroll
                    for (int i = 0; i < 2; ++i) {
                        acc[i][j] = __builtin_amdgcn_mfma_f32_16x16x32_f16(ah[i], bh, acc[i][j], 0, 0, 0);
                        acc[i][j] = __builtin_amdgcn_mfma_f32_16x16x32_f16(ah[i], bl, acc[i][j], 0, 0, 0);
                        acc[i][j] = __builtin_amdgcn_mfma_f32_16x16x32_f16(al[i], bh, acc[i][j], 0, 0, 0);
                    }
                }
                __builtin_amdgcn_s_setprio(0);
                __builtin_amdgcn_sched_barrier(0);
                barr();
            }
            // h1 = relu(acc+b1) -> sH (single f16); overwrite ctx region
            #pragma unroll
            for (int j = 0; j < 4; ++j) {
                int col = wcg * 64 + j * 16 + lr;
                float bv = sBias[col];
                #pragma unroll
                for (int i = 0; i < 2; ++i)
                    #pragma unroll
                    for (int q = 0; q < 4; ++q) {
                        float v = fmaxf(acc[i][j][q] + bv, 0.f);
                        int row = wrh * 32 + i * 16 + lh * 4 + q;
                        int e = ((row << 8) + col) ^ ((row & 7) << 3);
                        sH[e] = (f16)v;
                    }
            }
            stageB(W2hL, W2lL, bufs[0], 0, HDIM);
            stageB(W2hL, W2lL, bufs[1], 1, HDIM);
            lgkm_bar();   // publish h1

            // ================= GEMM2: K=256, 8 phases, A single ===========
            #pragma unroll
            for (int i = 0; i < 2; ++i)
                #pragma unroll
                for (int j = 0; j < 4; ++j) acc[i][j] = (f32x4){0.f, 0.f, 0.f, 0.f};
            #pragma unroll
            for (int kt = 0; kt < 8; ++kt) {
                if (kt + 2 < 8) stageB(W2hL, W2lL, bufs[(kt + 2) % 3], kt + 2, HDIM);
                if (kt < 6) vmw<8>(); else if (kt == 6) vmw<4>(); else vmw<0>();
                barr();
                int k0 = kt * 32 + lh * 8;
                f16x8 ah[2];
                #pragma unroll
                for (int i = 0; i < 2; ++i) {
                    int row = wrh * 32 + i * 16 + lr;
                    int e = ((row << 8) + k0) ^ ((row & 7) << 3);
                    ah[i] = *(const f16x8*)&sH[e];
                }
                const char* bb = bufs[kt % 3];
                __builtin_amdgcn_s_setprio(1);
                #pragma unroll
                for (int j = 0; j < 4; ++j) {
                    int cb = (wcg * 64 + j * 16 + lr) * 64 + bxor;
                    f16x8 bh = *(const f16x8*)(bb + cb);
                    f16x8 bl = *(const f16x8*)(bb + 16384 + cb);
                    #pragma unroll
                    for (int i = 0; i < 2; ++i) {
                        acc[i][j] = __builtin_amdgcn_mfma_f32_16x16x32_f16(ah[i], bh, acc[i][j], 0, 0, 0);
                        acc[i][j] = __builtin_amdgcn_mfma_f32_16x16x32_f16(ah[i], bl, acc[i][j], 0, 0, 0);
                    }
                }
                __builtin_amdgcn_s_setprio(0);
                __builtin_amdgcn_sched_barrier(0);
                barr();
            }
            // h2 = relu(acc+b2) -> sH
            #pragma unroll
            for (int j = 0; j < 4; ++j) {
                int col = wcg * 64 + j * 16 + lr;
                float bv = sBias[256 + col];
                #pragma unroll
                for (int i = 0; i < 2; ++i)
                    #pragma unroll
                    for (int q = 0; q < 4; ++q) {
                        float v = fmaxf(acc[i][j][q] + bv, 0.f);
                        int row = wrh * 32 + i * 16 + lh * 4 + q;
                        int e = ((row << 8) + col) ^ ((row & 7) << 3);
                        sH[e] = (f16)v;
                    }
            }
            stageB(W3hL, W3lL, bufs[0], 0, HDIM);
            stageB(W3hL, W3lL, bufs[1], 1, HDIM);
            lgkm_bar();   // publish h2

            // ================= GEMM3: K=256, 8 phases, A single ===========
            f32x4 acc3[2][3];
            #pragma unroll
            for (int i = 0; i < 2; ++i)
                #pragma unroll
                for (int j = 0; j < 3; ++j) acc3[i][j] = (f32x4){0.f, 0.f, 0.f, 0.f};
            #pragma unroll
            for (int kt = 0; kt < 8; ++kt) {
                if (kt + 2 < 8) stageB(W3hL, W3lL, bufs[(kt + 2) % 3], kt + 2, HDIM);
                if (kt < 6) vmw<8>(); else if (kt == 6) vmw<4>(); else vmw<0>();
                barr();
                int k0 = kt * 32 + lh * 8;
                f16x8 ah[2];
                #pragma unroll
                for (int i = 0; i < 2; ++i) {
                    int row = wrh * 32 + i * 16 + lr;
                    int e = ((row << 8) + k0) ^ ((row & 7) << 3);
                    ah[i] = *(const f16x8*)&sH[e];
                }
                const char* bb = bufs[kt % 3];
                __builtin_amdgcn_s_setprio(1);
                #pragma unroll
                for (int j = 0; j < 3; ++j) {
                    int cb = (wcg * 48 + j * 16 + lr) * 64 + bxor;
                    f16x8 bh = *(const f16x8*)(bb + cb);
                    f16x8 bl = *(const f16x8*)(bb + 16384 + cb);
                    #pragma unroll
                    for (int i = 0; i < 2; ++i) {
                        acc3[i][j] = __builtin_amdgcn_mfma_f32_16x16x32_f16(ah[i], bh, acc3[i][j], 0, 0, 0);
                        acc3[i][j] = __builtin_amdgcn_mfma_f32_16x16x32_f16(ah[i], bl, acc3[i][j], 0, 0, 0);
                    }
                }
                __builtin_amdgcn_s_setprio(0);
                __builtin_amdgcn_sched_barrier(0);
                barr();
            }
            // p = acc3 + b3 -> sP (overlays sH + sB0 head; all staging drained)
            #pragma unroll
            for (int j = 0; j < 3; ++j) {
                int col = wcg * 48 + j * 16 + lr;
                float bv = (col < N3) ? sBias[512 + col] : 0.f;
                #pragma unroll
                for (int i = 0; i < 2; ++i)
                    #pragma unroll
                    for (int q = 0; q < 4; ++q) {
                        int row = wrh * 32 + i * 16 + lh * 4 + q;
                        sP[row * PSTR + col] = acc3[i][j][q] + bv;
                    }
            }
            lgkm_bar();   // publish sP

            // ===== spline: one (row,t) per thread =====
            {
                int r = tid & 63, t = tid >> 6;
                float xin = sX[cur][r][2 * t + (l & 1)];
                const float* pp = &sP[r * PSTR + t * PD];
                bool inside = (xin >= -TBV) && (xin <= TBV);
                float xs = fminf(fmaxf(xin, -TBV), TBV);

                float e0, e1, e2, e3, e4, e5, e6, e7;
                {
                    float a0 = pp[0], a1 = pp[1], a2 = pp[2], a3 = pp[3];
                    float a4 = pp[4], a5 = pp[5], a6 = pp[6], a7 = pp[7];
                    float m = fmaxf(fmaxf(fmaxf(a0, a1), fmaxf(a2, a3)),
                                    fmaxf(fmaxf(a4, a5), fmaxf(a6, a7)));
                    e0 = expf(a0 - m); e1 = expf(a1 - m); e2 = expf(a2 - m); e3 = expf(a3 - m);
                    e4 = expf(a4 - m); e5 = expf(a5 - m); e6 = expf(a6 - m); e7 = expf(a7 - m);
                }
                float swv = ((e0 + e1) + (e2 + e3)) + ((e4 + e5) + (e6 + e7));
                float cwc = (1.f - 0.001f * KBINS) / swv;
                float x0 = -TBV, x1 = TBV;
                int idx = 0;
                bool done = false;
                {
                    float cs = 0.f;
                    float ee[7] = {e0, e1, e2, e3, e4, e5, e6};
                    #pragma unroll
                    for (int k = 0; k < 7; ++k) {
                        cs += 0.001f + cwc * ee[k];
                        float nxt = 2.f * TBV * cs - TBV;
                        bool ge = (xs >= nxt);
                        x0 = ge ? nxt : x0;
                        idx += ge ? 1 : 0;
                        x1 = (!ge && !done) ? nxt : x1;
                        done = done || !ge;
                    }
                }
                float y0 = -TBV, y1 = TBV;
                {
                    float a0 = pp[8], a1 = pp[9], a2 = pp[10], a3 = pp[11];
                    float a4 = pp[12], a5 = pp[13], a6 = pp[14], a7 = pp[15];
                    float m = fmaxf(fmaxf(fmaxf(a0, a1), fmaxf(a2, a3)),
                                    fmaxf(fmaxf(a4, a5), fmaxf(a6, a7)));
                    float f0 = expf(a0 - m), f1 = expf(a1 - m), f2 = expf(a2 - m), f3 = expf(a3 - m);
                    float f4 = expf(a4 - m), f5 = expf(a5 - m), f6 = expf(a6 - m), f7 = expf(a7 - m);
                    float shv = ((f0 + f1) + (f2 + f3)) + ((f4 + f5) + (f6 + f7));
                    float chc = (1.f - 0.001f * KBINS) / shv;
                    float cs = 0.f;
                    float ff[7] = {f0, f1, f2, f3, f4, f5, f6};
                    #pragma unroll
                    for (int k = 0; k < 7; ++k) {
                        cs += 0.001f + chc * ff[k];
                        float nxt = 2.f * TBV * cs - TBV;
                        y0 = (k < idx) ? nxt : y0;
                        y1 = (k == idx) ? nxt : y1;
                    }
                }
                float udm = pp[16 + (idx > 0 ? idx - 1 : 0)];
                float udp = pp[16 + (idx < 7 ? idx : 6)];
                float d0 = (idx > 0) ? 0.001f + softplusf(udm) : 1.f;
                float d1 = (idx < 7) ? 0.001f + softplusf(udp) : 1.f;

                float bw = x1 - x0, bh2 = y1 - y0;
                float delta = bh2 / bw;
                float th = (xs - x0) / bw;
                float th1m = th * (1.f - th);
                float num = bh2 * (delta * th * th + d0 * th1m);
                float den = delta + (d0 + d1 - 2.f * delta) * th1m;
                float y = y0 + num / den;
                float omth = 1.f - th;
                float dnum = delta * delta * (d1 * th * th + 2.f * delta * th1m + d0 * omth * omth);
                float ldv = logf(dnum) - 2.f * logf(den);
                sY[r][t] = inside ? y : xin;
                sLd[r][t] = inside ? ldv : 0.f;
            }
            lgkm_bar();   // publish sY/sLd

            // ===== rebuild x (+perm) and ldet =====
            {
                int r = tid >> 3, f0 = (tid & 7) * 2;
                if (l < NL - 1) {
                    #pragma unroll
                    for (int ff = 0; ff < 2; ++ff) {
                        int f = f0 + ff;
                        int g = sPerm[l * FDIM + f];
                        float v = ((g & 1) == (l & 1)) ? sY[r][g >> 1] : sX[cur][r][g];
                        sX[cur ^ 1][r][f] = v;
                    }
                    if (f0 == 0) {
                        float s = 0.f;
                        #pragma unroll
                        for (int t = 0; t < 8; ++t) s += sLd[r][t];
                        sLdet[r] += s;
                    }
                } else {
                    float ov[2];
                    #pragma unroll
                    for (int ff = 0; ff < 2; ++ff) {
                        int f = f0 + ff;
                        float v = ((f & 1) == (l & 1)) ? sY[r][f >> 1] : sX[cur][r][f];
                        ov[ff] = fminf(fmaxf(v, -1.f), 1.f);
                    }
                    float2 o = {ov[0], ov[1]};
                    *(float2*)&out[(size_t)(rbase + r) * FDIM + f0] = o;
                    if (f0 == 0) {
                        float s = 0.f;
                        #pragma unroll
                        for (int t = 0; t < 8; ++t) s += sLd[r][t];
                        out[(size_t)BATCH * FDIM + rbase + r] = sLdet[r] + s;
                    }
                }
            }
            cur ^= 1;
        }
    }
}

extern "C" void kernel_launch(void* const* d_in, const int* in_sizes, int n_in,
                              void* d_out, int out_size, void* d_ws, size_t ws_size,
                              hipStream_t stream) {
    (void)in_sizes; (void)n_in; (void)out_size; (void)ws_size;
    const float* inputs  = (const float*)d_in[0];
    const float* context = (const float*)d_in[1];
    const float* W1 = (const float*)d_in[2];
    const float* b1 = (const float*)d_in[3];
    const float* W2 = (const float*)d_in[4];
    const float* b2 = (const float*)d_in[5];
    const float* W3 = (const float*)d_in[6];
    const float* b3 = (const float*)d_in[7];
    const int*   perms = (const int*)d_in[8];
    float* out = (float*)d_out;

    f16* W1h = (f16*)d_ws;
    f16* W1l = W1h + (size_t)NL * HDIM * K1;
    f16* W2h = W1l + (size_t)NL * HDIM * K1;
    f16* W2l = W2h + (size_t)NL * HDIM * HDIM;
    f16* W3h = W2l + (size_t)NL * HDIM * HDIM;
    f16* W3l = W3h + (size_t)NL * N3P * HDIM;
    f16* ctxh = W3l + (size_t)NL * N3P * HDIM;
    f16* ctxl = ctxh + (size_t)BATCH * CDIM;

    int n1 = NL * HDIM * K1;
    conv_w1_kernel<<<(n1 + 255) / 256, 256, 0, stream>>>(W1, W1h, W1l);
    int n2 = NL * HDIM * HDIM;
    conv_w2_kernel<<<(n2 + 255) / 256, 256, 0, stream>>>(W2, W2h, W2l);
    int n3 = NL * N3P * HDIM;
    conv_w3_kernel<<<(n3 + 255) / 256, 256, 0, stream>>>(W3, W3h, W3l);
    int nc = BATCH * CDIM / 4;
    conv_ctx_kernel<<<(nc + 255) / 256, 256, 0, stream>>>(context, ctxh, ctxl);

    flow_kernel<<<256, 512, 0, stream>>>(
        inputs, ctxh, ctxl, W1h, W1l, W2h, W2l, W3h, W3l,
        b1, b2, b3, perms, out);
}

// Round 17
// 588.218 us; speedup vs baseline: 1.3363x; 1.2645x over previous
//
#include <hip/hip_runtime.h>
#include <math.h>

#define BATCH 65536
#define FDIM 16
#define CDIM 128
#define HDIM 256
#define NL 8
#define KBINS 8
#define TDIM 8
#define PD 23
#define TBV 3.0f
#define K1 160      // GEMM1 K: 128 ctx + 8 xi + 24 zero
#define N3 184      // real N of GEMM3
#define N3P 192     // padded N of GEMM3
#define PSTR 197    // p LDS row stride (f32 words)
#define MR 64       // rows per row-block
#define XSTR 40     // sXi row stride (f16)

typedef _Float16 f16;
typedef __attribute__((ext_vector_type(8))) _Float16 f16x8;
typedef __attribute__((ext_vector_type(4))) float f32x4;

// ---------------- weight conversion (transposed to [N][K], split hi/lo) ----
__global__ __launch_bounds__(256)
void conv_w1_kernel(const float* __restrict__ W1,
                    f16* __restrict__ Wh, f16* __restrict__ Wl) {
    int idx = blockIdx.x * 256 + threadIdx.x;
    if (idx >= NL * HDIM * K1) return;
    int l = idx / (HDIM * K1);
    int rem = idx - l * (HDIM * K1);
    int n = rem / K1;
    int k = rem - n * K1;
    int row = (k < 128) ? (8 + k) : ((k < 136) ? (k - 128) : -1);
    float v = (row >= 0) ? W1[((size_t)l * 136 + row) * HDIM + n] : 0.f;
    f16 hv = (f16)v;
    Wh[idx] = hv; Wl[idx] = (f16)(v - (float)hv);
}

__global__ __launch_bounds__(256)
void conv_w2_kernel(const float* __restrict__ W2,
                    f16* __restrict__ Wh, f16* __restrict__ Wl) {
    int idx = blockIdx.x * 256 + threadIdx.x;
    if (idx >= NL * HDIM * HDIM) return;
    int l = idx / (HDIM * HDIM);
    int rem = idx - l * (HDIM * HDIM);
    int n = rem >> 8;
    int k = rem & 255;
    float v = W2[((size_t)l * HDIM + k) * HDIM + n];
    f16 hv = (f16)v;
    Wh[idx] = hv; Wl[idx] = (f16)(v - (float)hv);
}

__global__ __launch_bounds__(256)
void conv_w3_kernel(const float* __restrict__ W3,
                    f16* __restrict__ Wh, f16* __restrict__ Wl) {
    int idx = blockIdx.x * 256 + threadIdx.x;
    if (idx >= NL * N3P * HDIM) return;
    int l = idx / (N3P * HDIM);
    int rem = idx - l * (N3P * HDIM);
    int n = rem >> 8;
    int k = rem & 255;
    float v = (n < N3) ? W3[((size_t)l * HDIM + k) * N3 + n] : 0.f;
    f16 hv = (f16)v;
    Wh[idx] = hv; Wl[idx] = (f16)(v - (float)hv);
}

__global__ __launch_bounds__(256)
void conv_ctx_kernel(const float* __restrict__ ctx,
                     f16* __restrict__ ch, f16* __restrict__ cl) {
    size_t idx = ((size_t)blockIdx.x * 256 + threadIdx.x) * 4;
    if (idx >= (size_t)BATCH * CDIM) return;
    float4 v = *(const float4*)&ctx[idx];
    f16 h;
    h = (f16)v.x; ch[idx + 0] = h; cl[idx + 0] = (f16)(v.x - (float)h);
    h = (f16)v.y; ch[idx + 1] = h; cl[idx + 1] = (f16)(v.y - (float)h);
    h = (f16)v.z; ch[idx + 2] = h; cl[idx + 2] = (f16)(v.z - (float)h);
    h = (f16)v.w; ch[idx + 3] = h; cl[idx + 3] = (f16)(v.w - (float)h);
}

__device__ __forceinline__ float softplusf(float v) {
    return fmaxf(v, 0.f) + log1pf(expf(-fabsf(v)));
}

__device__ __forceinline__ void gld16(const f16* src, f16* dst) {
    __builtin_amdgcn_global_load_lds(
        (const __attribute__((address_space(1))) unsigned int*)src,
        (__attribute__((address_space(3))) unsigned int*)dst, 16, 0, 0);
}

template<int N> __device__ __forceinline__ void vmw() {
    asm volatile("s_waitcnt vmcnt(%0)" :: "n"(N) : "memory");
    __builtin_amdgcn_sched_barrier(0);
}
__device__ __forceinline__ void barr() {
    __builtin_amdgcn_s_barrier();
    __builtin_amdgcn_sched_barrier(0);
}
__device__ __forceinline__ void lgkm_bar() {
    asm volatile("s_waitcnt lgkmcnt(0)" ::: "memory");
    __builtin_amdgcn_s_barrier();
    __builtin_amdgcn_sched_barrier(0);
}

// ---------------- fused flow kernel ----------------
// Persistent: grid 256 (1 WG/CU), 512 threads (8 waves). Each wave OWNS a
// 32-col slice of N and its own triple-buffered LDS weight tile -> the
// K-loops have ZERO barriers (per-wave counted vmcnt only). Barriers only at
// GEMM boundaries (~9/layer). ctx restaged per layer (shared, one
// vmw+barrier). h1/h2 single f16, xi split-f16.
__global__ __launch_bounds__(512, 1)
void flow_kernel(const float* __restrict__ in,
                 const f16* __restrict__ ctxh, const f16* __restrict__ ctxl,
                 const f16* __restrict__ W1h, const f16* __restrict__ W1l,
                 const f16* __restrict__ W2h, const f16* __restrict__ W2l,
                 const f16* __restrict__ W3h, const f16* __restrict__ W3l,
                 const float* __restrict__ b1, const float* __restrict__ b2,
                 const float* __restrict__ b3, const int* __restrict__ perms,
                 float* __restrict__ out) {
    // arena: [0,32K) ctx(2pl) / sH / sP-head | [32K..128K) 8 waves x 3 x 4KB B
    __shared__ __align__(16) char arena[131072];
    __shared__ __align__(16) f16 sXi[2][MR * XSTR];   // 10.2KB
    __shared__ float sX[2][MR][17];
    __shared__ float sY[MR][9];
    __shared__ float sLd[MR][9];
    __shared__ float sLdet[MR];
    __shared__ float sBias[768];
    __shared__ int   sPerm[(NL - 1) * FDIM];

    f16* sH = (f16*)arena;
    float* sP = (float*)arena;

    const int tid = threadIdx.x;
    const int lane = tid & 63;
    const int w = tid >> 6;                      // 0..7
    const int lr = lane & 15, lh = lane >> 4;
    const int bid = blockIdx.x;
    const int wgid = (bid & 7) * 32 + (bid >> 3);   // XCD swizzle, grid 256
    const int wcol0 = w * 32;                    // wave's private col slice
    const int bxor = (lh ^ (lr & 3)) << 4;       // B read de-swizzle

    char* const wbuf = arena + 32768 + w * 12288;   // 3 x 4KB private bufs

    // stage wave's own 32-col B tile (k-tile kt) into private buf b
    auto stageB = [&](const f16* Wh, const f16* Wl, int b, int kt, int KD) {
        char* dst = wbuf + b * 4096;
        #pragma unroll
        for (int ii = 0; ii < 2; ++ii) {
            int si = ii * 64 + lane;
            int c = si >> 2, seg = si & 3;
            const f16* sh = Wh + (size_t)(wcol0 + c) * KD + kt * 32 + (seg ^ (c & 3)) * 8;
            const f16* sl = Wl + (size_t)(wcol0 + c) * KD + kt * 32 + (seg ^ (c & 3)) * 8;
            gld16(sh, (f16*)(dst + ii * 1024 + lane * 16));
            gld16(sl, (f16*)(dst + 2048 + ii * 1024 + lane * 16));
        }
    };

    for (int rb = 0; rb < 4; ++rb) {
        const int rbase = (rb * 256 + wgid) * MR;
        lgkm_bar();   // protect sX/sLdet reuse across row-blocks

        // ---- init x, ldet, perms ----
        {
            int r = tid >> 3, c2 = (tid & 7) * 2;
            float2 v = *(const float2*)&in[(size_t)(rbase + r) * FDIM + c2];
            sX[0][r][c2 + 0] = fminf(fmaxf(v.x, -1.f), 1.f);
            sX[0][r][c2 + 1] = fminf(fmaxf(v.y, -1.f), 1.f);
        }
        if (tid < MR) sLdet[tid] = 0.f;
        if (rb == 0 && tid < (NL - 1) * FDIM) sPerm[tid] = perms[tid];

        int cur = 0;
        for (int l = 0; l < NL; ++l) {
            lgkm_bar();   // publish rebuild/init LDS writes

            // ---- biases -> LDS (consumed immediately; no gld16 in flight) --
            {
                float bv1 = (tid < 256) ? b1[l * HDIM + tid]
                                        : b2[l * HDIM + (tid - 256)];
                float bv3 = b3[l * N3 + (tid < N3 ? tid : N3 - 1)];
                sBias[tid] = bv1;
                if (tid < N3) sBias[512 + tid] = bv3;
            }
            // ---- xi (split) into sXi + zero pad ----
            if (tid < MR) {
                int r = tid, off = 1 - (l & 1);
                #pragma unroll
                for (int k = 0; k < 8; ++k) {
                    float v = sX[cur][r][2 * k + off];
                    f16 hv = (f16)v;
                    sXi[0][r * XSTR + k] = hv;
                    sXi[1][r * XSTR + k] = (f16)(v - (float)hv);
                }
                #pragma unroll
                for (int k = 8; k < 32; ++k) {
                    sXi[0][r * XSTR + k] = (f16)0.f;
                    sXi[1][r * XSTR + k] = (f16)0.f;
                }
            }
            // ---- stage ctx into arena[0,32K): row-major, swizzled src ----
            #pragma unroll
            for (int s = 0; s < 4; ++s) {
                int slot = s * 512 + tid;
                int p = slot >> 10, sp = slot & 1023;
                int row = sp >> 4, blk = sp & 15;
                const f16* src = (p ? ctxl : ctxh)
                               + (size_t)(rbase + row) * CDIM + (blk ^ (row & 7)) * 8;
                gld16(src, (f16*)(arena + slot * 16));
            }
            const f16* W1hL = W1h + (size_t)l * HDIM * K1;
            const f16* W1lL = W1l + (size_t)l * HDIM * K1;
            const f16* W2hL = W2h + (size_t)l * HDIM * HDIM;
            const f16* W2lL = W2l + (size_t)l * HDIM * HDIM;
            const f16* W3hL = W3h + (size_t)l * N3P * HDIM;
            const f16* W3lL = W3l + (size_t)l * N3P * HDIM;
            stageB(W1hL, W1lL, 0, 0, K1);
            stageB(W1hL, W1lL, 1, 1, K1);
            vmw<8>();     // own ctx slice landed (W1 s0/s1 keep flying)
            lgkm_bar();   // ctx visible to all waves; xi/bias published

            f32x4 acc[4][2];
            // ======= GEMM1: K=160, 5 phases, A split, NO barriers =========
            #pragma unroll
            for (int i = 0; i < 4; ++i)
                #pragma unroll
                for (int j = 0; j < 2; ++j) acc[i][j] = (f32x4){0.f, 0.f, 0.f, 0.f};
            #pragma unroll
            for (int kt = 0; kt < 5; ++kt) {
                if (kt < 3) stageB(W1hL, W1lL, (kt + 2) % 3, kt + 2, K1);
                if (kt < 3) vmw<8>(); else if (kt == 3) vmw<4>(); else vmw<0>();
                f16x8 ah[4], al[4];
                if (kt < 4) {
                    #pragma unroll
                    for (int i = 0; i < 4; ++i) {
                        int row = i * 16 + lr;
                        int byo = row * 256 + ((kt * 64 + lh * 16) ^ ((row & 7) << 4));
                        ah[i] = *(const f16x8*)(arena + byo);
                        al[i] = *(const f16x8*)(arena + 16384 + byo);
                    }
                } else {
                    #pragma unroll
                    for (int i = 0; i < 4; ++i) {
                        int row = i * 16 + lr;
                        ah[i] = *(const f16x8*)&sXi[0][row * XSTR + lh * 8];
                        al[i] = *(const f16x8*)&sXi[1][row * XSTR + lh * 8];
                    }
                }
                const char* bb = wbuf + (kt % 3) * 4096;
                __builtin_amdgcn_s_setprio(1);
                #pragma unroll
                for (int j = 0; j < 2; ++j) {
                    int cb = (j * 16 + lr) * 64 + bxor;
                    f16x8 bh = *(const f16x8*)(bb + cb);
                    f16x8 bl = *(const f16x8*)(bb + 2048 + cb);
                    #pragma unroll
                    for (int i = 0; i < 4; ++i) {
                        acc[i][j] = __builtin_amdgcn_mfma_f32_16x16x32_f16(ah[i], bh, acc[i][j], 0, 0, 0);
                        acc[i][j] = __builtin_amdgcn_mfma_f32_16x16x32_f16(ah[i], bl, acc[i][j], 0, 0, 0);
                        acc[i][j] = __builtin_amdgcn_mfma_f32_16x16x32_f16(al[i], bh, acc[i][j], 0, 0, 0);
                    }
                }
                __builtin_amdgcn_s_setprio(0);
                __builtin_amdgcn_sched_barrier(0);
            }
            barr();   // all waves done reading ctx/xi
            // h1 = relu(acc+b1) -> sH (overwrites ctx region)
            #pragma unroll
            for (int j = 0; j < 2; ++j) {
                int col = wcol0 + j * 16 + lr;
                float bv = sBias[col];
                #pragma unroll
                for (int i = 0; i < 4; ++i)
                    #pragma unroll
                    for (int q = 0; q < 4; ++q) {
                        float v = fmaxf(acc[i][j][q] + bv, 0.f);
                        int row = i * 16 + lh * 4 + q;
                        int e = ((row << 8) + col) ^ ((row & 7) << 3);
                        sH[e] = (f16)v;
                    }
            }
            stageB(W2hL, W2lL, 0, 0, HDIM);
            stageB(W2hL, W2lL, 1, 1, HDIM);
            lgkm_bar();   // publish h1

            // ======= GEMM2: K=256, 8 phases, A single, NO barriers ========
            #pragma unroll
            for (int i = 0; i < 4; ++i)
                #pragma unroll
                for (int j = 0; j < 2; ++j) acc[i][j] = (f32x4){0.f, 0.f, 0.f, 0.f};
            #pragma unroll
            for (int kt = 0; kt < 8; ++kt) {
                if (kt < 6) stageB(W2hL, W2lL, (kt + 2) % 3, kt + 2, HDIM);
                if (kt < 6) vmw<8>(); else if (kt == 6) vmw<4>(); else vmw<0>();
                int k0 = kt * 32 + lh * 8;
                f16x8 ah[4];
                #pragma unroll
                for (int i = 0; i < 4; ++i) {
                    int row = i * 16 + lr;
                    int e = ((row << 8) + k0) ^ ((row & 7) << 3);
                    ah[i] = *(const f16x8*)&sH[e];
                }
                const char* bb = wbuf + (kt % 3) * 4096;
                __builtin_amdgcn_s_setprio(1);
                #pragma unroll
                for (int j = 0; j < 2; ++j) {
                    int cb = (j * 16 + lr) * 64 + bxor;
                    f16x8 bh = *(const f16x8*)(bb + cb);
                    f16x8 bl = *(const f16x8*)(bb + 2048 + cb);
                    #pragma unroll
                    for (int i = 0; i < 4; ++i) {
                        acc[i][j] = __builtin_amdgcn_mfma_f32_16x16x32_f16(ah[i], bh, acc[i][j], 0, 0, 0);
                        acc[i][j] = __builtin_amdgcn_mfma_f32_16x16x32_f16(ah[i], bl, acc[i][j], 0, 0, 0);
                    }
                }
                __builtin_amdgcn_s_setprio(0);
                __builtin_amdgcn_sched_barrier(0);
            }
            barr();   // all waves done reading h1
            // h2 = relu(acc+b2) -> sH
            #pragma unroll
            for (int j = 0; j < 2; ++j) {
                int col = wcol0 + j * 16 + lr;
                float bv = sBias[256 + col];
                #pragma unroll
                for (int i = 0; i < 4; ++i)
                    #pragma unroll
                    for (int q = 0; q < 4; ++q) {
                        float v = fmaxf(acc[i][j][q] + bv, 0.f);
                        int row = i * 16 + lh * 4 + q;
                        int e = ((row << 8) + col) ^ ((row & 7) << 3);
                        sH[e] = (f16)v;
                    }
            }
            if (w < 6) {
                stageB(W3hL, W3lL, 0, 0, HDIM);
                stageB(W3hL, W3lL, 1, 1, HDIM);
            }
            lgkm_bar();   // publish h2

            // ======= GEMM3: K=256, 8 phases, waves 0-5, NO barriers =======
            f32x4 acc3[4][2];
            #pragma unroll
            for (int i = 0; i < 4; ++i)
                #pragma unroll
                for (int j = 0; j < 2; ++j) acc3[i][j] = (f32x4){0.f, 0.f, 0.f, 0.f};
            if (w < 6) {
                #pragma unroll
                for (int kt = 0; kt < 8; ++kt) {
                    if (kt < 6) stageB(W3hL, W3lL, (kt + 2) % 3, kt + 2, HDIM);
                    if (kt < 6) vmw<8>(); else if (kt == 6) vmw<4>(); else vmw<0>();
                    int k0 = kt * 32 + lh * 8;
                    f16x8 ah[4];
                    #pragma unroll
                    for (int i = 0; i < 4; ++i) {
                        int row = i * 16 + lr;
                        int e = ((row << 8) + k0) ^ ((row & 7) << 3);
                        ah[i] = *(const f16x8*)&sH[e];
                    }
                    const char* bb = wbuf + (kt % 3) * 4096;
                    __builtin_amdgcn_s_setprio(1);
                    #pragma unroll
                    for (int j = 0; j < 2; ++j) {
                        int cb = (j * 16 + lr) * 64 + bxor;
                        f16x8 bh = *(const f16x8*)(bb + cb);
                        f16x8 bl = *(const f16x8*)(bb + 2048 + cb);
                        #pragma unroll
                        for (int i = 0; i < 4; ++i) {
                            acc3[i][j] = __builtin_amdgcn_mfma_f32_16x16x32_f16(ah[i], bh, acc3[i][j], 0, 0, 0);
                            acc3[i][j] = __builtin_amdgcn_mfma_f32_16x16x32_f16(ah[i], bl, acc3[i][j], 0, 0, 0);
                        }
                    }
                    __builtin_amdgcn_s_setprio(0);
                    __builtin_amdgcn_sched_barrier(0);
                }
            }
            barr();   // all waves done reading h2
            // p = acc3 + b3 -> sP (overlays sH + dead low bufs)
            if (w < 6) {
                #pragma unroll
                for (int j = 0; j < 2; ++j) {
                    int col = wcol0 + j * 16 + lr;
                    float bv = (col < N3) ? sBias[512 + col] : 0.f;
                    #pragma unroll
                    for (int i = 0; i < 4; ++i)
                        #pragma unroll
                        for (int q = 0; q < 4; ++q) {
                            int row = i * 16 + lh * 4 + q;
                            sP[row * PSTR + col] = acc3[i][j][q] + bv;
                        }
                }
            }
            lgkm_bar();   // publish sP

            // ===== spline: one (row,t) per thread =====
            {
                int r = tid & 63, t = tid >> 6;
                float xin = sX[cur][r][2 * t + (l & 1)];
                const float* pp = &sP[r * PSTR + t * PD];
                bool inside = (xin >= -TBV) && (xin <= TBV);
                float xs = fminf(fmaxf(xin, -TBV), TBV);

                float e0, e1, e2, e3, e4, e5, e6, e7;
                {
                    float a0 = pp[0], a1 = pp[1], a2 = pp[2], a3 = pp[3];
                    float a4 = pp[4], a5 = pp[5], a6 = pp[6], a7 = pp[7];
                    float m = fmaxf(fmaxf(fmaxf(a0, a1), fmaxf(a2, a3)),
                                    fmaxf(fmaxf(a4, a5), fmaxf(a6, a7)));
                    e0 = expf(a0 - m); e1 = expf(a1 - m); e2 = expf(a2 - m); e3 = expf(a3 - m);
                    e4 = expf(a4 - m); e5 = expf(a5 - m); e6 = expf(a6 - m); e7 = expf(a7 - m);
                }
                float swv = ((e0 + e1) + (e2 + e3)) + ((e4 + e5) + (e6 + e7));
                float cwc = (1.f - 0.001f * KBINS) / swv;
                float x0 = -TBV, x1 = TBV;
                int idx = 0;
                bool done = false;
                {
                    float cs = 0.f;
                    float ee[7] = {e0, e1, e2, e3, e4, e5, e6};
                    #pragma unroll
                    for (int k = 0; k < 7; ++k) {
                        cs += 0.001f + cwc * ee[k];
                        float nxt = 2.f * TBV * cs - TBV;
                        bool ge = (xs >= nxt);
                        x0 = ge ? nxt : x0;
                        idx += ge ? 1 : 0;
                        x1 = (!ge && !done) ? nxt : x1;
                        done = done || !ge;
                    }
                }
                float y0 = -TBV, y1 = TBV;
                {
                    float a0 = pp[8], a1 = pp[9], a2 = pp[10], a3 = pp[11];
                    float a4 = pp[12], a5 = pp[13], a6 = pp[14], a7 = pp[15];
                    float m = fmaxf(fmaxf(fmaxf(a0, a1), fmaxf(a2, a3)),
                                    fmaxf(fmaxf(a4, a5), fmaxf(a6, a7)));
                    float f0 = expf(a0 - m), f1 = expf(a1 - m), f2 = expf(a2 - m), f3 = expf(a3 - m);
                    float f4 = expf(a4 - m), f5 = expf(a5 - m), f6 = expf(a6 - m), f7 = expf(a7 - m);
                    float shv = ((f0 + f1) + (f2 + f3)) + ((f4 + f5) + (f6 + f7));
                    float chc = (1.f - 0.001f * KBINS) / shv;
                    float cs = 0.f;
                    float ff[7] = {f0, f1, f2, f3, f4, f5, f6};
                    #pragma unroll
                    for (int k = 0; k < 7; ++k) {
                        cs += 0.001f + chc * ff[k];
                        float nxt = 2.f * TBV * cs - TBV;
                        y0 = (k < idx) ? nxt : y0;
                        y1 = (k == idx) ? nxt : y1;
                    }
                }
                float udm = pp[16 + (idx > 0 ? idx - 1 : 0)];
                float udp = pp[16 + (idx < 7 ? idx : 6)];
                float d0 = (idx > 0) ? 0.001f + softplusf(udm) : 1.f;
                float d1 = (idx < 7) ? 0.001f + softplusf(udp) : 1.f;

                float bw = x1 - x0, bh2 = y1 - y0;
                float delta = bh2 / bw;
                float th = (xs - x0) / bw;
                float th1m = th * (1.f - th);
                float num = bh2 * (delta * th * th + d0 * th1m);
                float den = delta + (d0 + d1 - 2.f * delta) * th1m;
                float y = y0 + num / den;
                float omth = 1.f - th;
                float dnum = delta * delta * (d1 * th * th + 2.f * delta * th1m + d0 * omth * omth);
                float ldv = logf(dnum) - 2.f * logf(den);
                sY[r][t] = inside ? y : xin;
                sLd[r][t] = inside ? ldv : 0.f;
            }
            lgkm_bar();   // publish sY/sLd

            // ===== rebuild x (+perm) and ldet =====
            {
                int r = tid >> 3, f0 = (tid & 7) * 2;
                if (l < NL - 1) {
                    #pragma unroll
                    for (int ff = 0; ff < 2; ++ff) {
                        int f = f0 + ff;
                        int g = sPerm[l * FDIM + f];
                        float v = ((g & 1) == (l & 1)) ? sY[r][g >> 1] : sX[cur][r][g];
                        sX[cur ^ 1][r][f] = v;
                    }
                    if (f0 == 0) {
                        float s = 0.f;
                        #pragma unroll
                        for (int t = 0; t < 8; ++t) s += sLd[r][t];
                        sLdet[r] += s;
                    }
                } else {
                    float ov[2];
                    #pragma unroll
                    for (int ff = 0; ff < 2; ++ff) {
                        int f = f0 + ff;
                        float v = ((f & 1) == (l & 1)) ? sY[r][f >> 1] : sX[cur][r][f];
                        ov[ff] = fminf(fmaxf(v, -1.f), 1.f);
                    }
                    float2 o = {ov[0], ov[1]};
                    *(float2*)&out[(size_t)(rbase + r) * FDIM + f0] = o;
                    if (f0 == 0) {
                        float s = 0.f;
                        #pragma unroll
                        for (int t = 0; t < 8; ++t) s += sLd[r][t];
                        out[(size_t)BATCH * FDIM + rbase + r] = sLdet[r] + s;
                    }
                }
            }
            cur ^= 1;
        }
    }
}

extern "C" void kernel_launch(void* const* d_in, const int* in_sizes, int n_in,
                              void* d_out, int out_size, void* d_ws, size_t ws_size,
                              hipStream_t stream) {
    (void)in_sizes; (void)n_in; (void)out_size; (void)ws_size;
    const float* inputs  = (const float*)d_in[0];
    const float* context = (const float*)d_in[1];
    const float* W1 = (const float*)d_in[2];
    const float* b1 = (const float*)d_in[3];
    const float* W2 = (const float*)d_in[4];
    const float* b2 = (const float*)d_in[5];
    const float* W3 = (const float*)d_in[6];
    const float* b3 = (const float*)d_in[7];
    const int*   perms = (const int*)d_in[8];
    float* out = (float*)d_out;

    f16* W1h = (f16*)d_ws;
    f16* W1l = W1h + (size_t)NL * HDIM * K1;
    f16* W2h = W1l + (size_t)NL * HDIM * K1;
    f16* W2l = W2h + (size_t)NL * HDIM * HDIM;
    f16* W3h = W2l + (size_t)NL * HDIM * HDIM;
    f16* W3l = W3h + (size_t)NL * N3P * HDIM;
    f16* ctxh = W3l + (size_t)NL * N3P * HDIM;
    f16* ctxl = ctxh + (size_t)BATCH * CDIM;

    int n1 = NL * HDIM * K1;
    conv_w1_kernel<<<(n1 + 255) / 256, 256, 0, stream>>>(W1, W1h, W1l);
    int n2 = NL * HDIM * HDIM;
    conv_w2_kernel<<<(n2 + 255) / 256, 256, 0, stream>>>(W2, W2h, W2l);
    int n3 = NL * N3P * HDIM;
    conv_w3_kernel<<<(n3 + 255) / 256, 256, 0, stream>>>(W3, W3h, W3l);
    int nc = BATCH * CDIM / 4;
    conv_ctx_kernel<<<(nc + 255) / 256, 256, 0, stream>>>(context, ctxh, ctxl);

    flow_kernel<<<256, 512, 0, stream>>>(
        inputs, ctxh, ctxl, W1h, W1l, W2h, W2l, W3h, W3l,
        b1, b2, b3, perms, out);
}